// Round 7
// baseline (3464.544 us; speedup 1.0000x reference)
//
#include <hip/hip_runtime.h>

#define N1 32768
#define NP1 512
#define NS1 32
#define N2 512
#define NP2 256
#define NS2 64

// ---- exact-rounding helpers: replicate reference op-by-op (NO fma/contract) ----
__device__ __forceinline__ float fadd(float a, float b){ return __fadd_rn(a,b); }
__device__ __forceinline__ float fmul(float a, float b){ return __fmul_rn(a,b); }
__device__ __forceinline__ float fsub(float a, float b){ return __fsub_rn(a,b); }

__device__ __forceinline__ float dist3(float px,float py,float pz,float cx,float cy,float cz){
    float dx = fsub(px,cx), dy = fsub(py,cy), dz = fsub(pz,cz);
    return fadd(fadd(fmul(dx,dx), fmul(dy,dy)), fmul(dz,dz));
}
__device__ __forceinline__ float sumsq3(float x,float y,float z){
    return fadd(fadd(fmul(x,x), fmul(y,y)), fmul(z,z));
}
__device__ __forceinline__ float dot3(float ax,float ay,float az,float bx,float by,float bz){
    return fadd(fadd(fmul(ax,bx), fmul(ay,by)), fmul(az,bz));
}

__device__ __forceinline__ unsigned long long shflmax64(unsigned long long k, int off){
    unsigned long long o = __shfl_xor(k, off, 64);
    return o > k ? o : k;
}

// =====================  FPS over 32768 pts, 512 picks  =====================
// v7: R6 structure + XCD-affinity swizzle. 1-D grid of 128 blocks; block
// lin -> batch b = lin%8, chunk m = lin/8. With round-robin block->XCD
// dispatch this puts ALL 16 blocks of a batch on ONE XCD, so the per-iter
// key exchange stays in that XCD's L2 (~200 cyc) instead of crossing dies
// (~600-900 cyc). Heuristic only: if dispatch differs, behavior = R6.
#define FPS1_M  16
#define FPS1_TB 256

__global__ __launch_bounds__(FPS1_TB) void fps1_kernel(const float* __restrict__ xyz,
                                                       float* __restrict__ new_xyz1,
                                                       unsigned long long* __restrict__ bests)
{
    const int lin = blockIdx.x;
    const int b = lin & 7;             // batch  (8 batches <-> 8 XCDs)
    const int m = lin >> 3;            // chunk within batch
    const int t = threadIdx.x;
    const int lane = t & 63;
    const int wid  = t >> 6;           // 4 waves
    const float* xb = xyz + (size_t)b * 6 * N1;

    __shared__ unsigned long long wb[4];
    __shared__ float cw[4];

    const int base = m * (N1 / FPS1_M);   // 2048-pt chunk
    float px[8], py[8], pz[8], dd[8];
#pragma unroll
    for (int j = 0; j < 8; ++j) {
        int n = base + t + j * FPS1_TB;
        px[j] = xb[n];
        py[j] = xb[N1 + n];
        pz[j] = xb[2*N1 + n];
        dd[j] = 1e10f;
    }

    float cx = xb[0], cy = xb[N1], cz = xb[2*N1];   // first pick = index 0

    for (int s = 0; s < NP1; ++s) {
        if (m == 0 && t == 0) {
            float* o = new_xyz1 + ((size_t)b*NP1 + s)*3;
            o[0] = cx; o[1] = cy; o[2] = cz;
        }
        if (s == NP1 - 1) break;

        // update min-dists, in-thread argmax (ascending n -> first-max kept)
        float bv = -1.0f; int bi = base + t;
#pragma unroll
        for (int j = 0; j < 8; ++j) {
            float d  = dist3(px[j],py[j],pz[j],cx,cy,cz);
            float nd = fminf(dd[j], d);
            dd[j] = nd;
            if (nd > bv) { bv = nd; bi = base + t + j*FPS1_TB; }
        }
        // packed key: float bits order-isomorphic (dist>=0); tie -> min index
        unsigned long long pk = ((unsigned long long)__float_as_uint(bv) << 15)
                              | (unsigned long long)(32767 - bi);
        pk = shflmax64(pk, 1);  pk = shflmax64(pk, 2);  pk = shflmax64(pk, 4);
        pk = shflmax64(pk, 8);  pk = shflmax64(pk, 16); pk = shflmax64(pk, 32);
        if (lane == 0) wb[wid] = pk;
        __syncthreads();

        if (wid == 0) {
            unsigned long long k4 = (lane < 4) ? wb[lane] : 0ull;
            k4 = shflmax64(k4, 1); k4 = shflmax64(k4, 2);
            unsigned long long* slotPar = bests + ((size_t)b*2 + (s & 1))*FPS1_M;
            if (lane == 0)
                __hip_atomic_store(slotPar + m, (k4 << 10) | (unsigned long long)s,
                                   __ATOMIC_RELAXED, __HIP_MEMORY_SCOPE_AGENT);
            // parallel poll: lane q watches slot q; speculative centroid load
            unsigned long long myv = 0; bool done = (lane >= FPS1_M);
            float ccx = 0.f, ccy = 0.f, ccz = 0.f;
            while (__ballot(done) != 0xFFFFFFFFFFFFFFFFull) {
                if (!done) {
                    unsigned long long v = __hip_atomic_load(slotPar + lane,
                                             __ATOMIC_RELAXED, __HIP_MEMORY_SCOPE_AGENT);
                    if ((unsigned)(v & 1023ull) == (unsigned)s) {
                        done = true; myv = v;
                        int idx = 32767 - (int)((v >> 10) & 0x7fffull);
                        ccx = xb[idx]; ccy = xb[N1 + idx]; ccz = xb[2*N1 + idx];
                    }
                }
            }
            unsigned long long w = myv;
            w = shflmax64(w, 1); w = shflmax64(w, 2); w = shflmax64(w, 4); w = shflmax64(w, 8);
            int wl = (int)__ffsll(__ballot(myv == w)) - 1;   // keys unique; lanes>=16 have 0
            float ncx = __shfl(ccx, wl, 64);
            float ncy = __shfl(ccy, wl, 64);
            float ncz = __shfl(ccz, wl, 64);
            if (lane == 0) { cw[0] = ncx; cw[1] = ncy; cw[2] = ncz; }
        }
        __syncthreads();
        cx = cw[0]; cy = cw[1]; cz = cw[2];
    }
}

// =====================  FPS over 512 pts, 256 picks: 1 wave/batch  =====================
__global__ __launch_bounds__(64) void fps2_kernel(const float* __restrict__ new_xyz1,
                                                  float* __restrict__ new_xyz2,
                                                  float* __restrict__ out0)
{
    const int b = blockIdx.x;
    const int t = threadIdx.x;
    __shared__ float c3[N2*3];
    const float* src = new_xyz1 + (size_t)b*N2*3;
    for (int e = t; e < N2*3; e += 64) c3[e] = src[e];
    __syncthreads();

    float px[8], py[8], pz[8], dd[8];
#pragma unroll
    for (int j = 0; j < 8; ++j) {
        int n = t + j*64;
        px[j] = c3[n*3]; py[j] = c3[n*3+1]; pz[j] = c3[n*3+2];
        dd[j] = 1e10f;
    }
    int cur = 0;
    for (int s = 0; s < NP2; ++s) {
        float cx = c3[cur*3], cy = c3[cur*3+1], cz = c3[cur*3+2];
        if (t == 0) {
            float* o = new_xyz2 + ((size_t)b*NP2 + s)*3;
            o[0]=cx; o[1]=cy; o[2]=cz;
            out0[b*3*NP2 + s]         = cx;   // l2_xyz transposed (8,3,256)
            out0[b*3*NP2 + NP2 + s]   = cy;
            out0[b*3*NP2 + 2*NP2 + s] = cz;
        }
        float bv = -1.0f; int bi = 0x7fffffff;
#pragma unroll
        for (int j = 0; j < 8; ++j) {
            float d  = dist3(px[j],py[j],pz[j],cx,cy,cz);
            float nd = fminf(dd[j], d);
            dd[j] = nd;
            int n = t + j*64;
            if (nd > bv) { bv = nd; bi = n; }
        }
#pragma unroll
        for (int m = 1; m < 64; m <<= 1) {
            float ov = __shfl_xor(bv, m, 64);
            int   oi = __shfl_xor(bi, m, 64);
            if (ov > bv || (ov == bv && oi < bi)) { bv = ov; bi = oi; }
        }
        cur = bi;
    }
}

// =====================  ball query 1: 1 wave per centroid  =====================
__global__ __launch_bounds__(64) void ball1_kernel(const float* __restrict__ xyz,
                                                   const float* __restrict__ new_xyz1,
                                                   int* __restrict__ idx1, float r2)
{
    const int s = blockIdx.x, b = blockIdx.y;
    const int lane = threadIdx.x;
    const float* xb = xyz + (size_t)b*6*N1;
    const float* cp = new_xyz1 + ((size_t)b*NP1 + s)*3;
    float cx = cp[0], cy = cp[1], cz = cp[2];
    float snew = sumsq3(cx,cy,cz);
    int* out = idx1 + ((size_t)b*NP1 + s)*NS1;
    int cnt = 0, first = 0;
    for (int ch = 0; ch < N1/64; ++ch) {
        int n = ch*64 + lane;
        float x = xb[n], y = xb[N1+n], z = xb[2*N1+n];
        float sx  = sumsq3(x,y,z);
        float dt  = dot3(cx,cy,cz,x,y,z);
        float sqr = fsub(fadd(snew, sx), fmul(2.0f, dt));   // (|c|^2+|p|^2) - 2*dot
        bool inb = !(sqr > r2);
        unsigned long long mask = __ballot(inb);
        if (mask) {
            if (cnt == 0) first = ch*64 + (int)(__ffsll((unsigned long long)mask) - 1);
            if (inb) {
                int pos = cnt + (int)__popcll(mask & ((1ull << lane) - 1ull));
                if (pos < NS1) out[pos] = n;
            }
            cnt += (int)__popcll(mask);
            if (cnt >= NS1) break;
        }
    }
    int c = cnt < NS1 ? cnt : NS1;
    if (lane < NS1 && lane >= c) out[lane] = first;
}

// =====================  ball query 2  =====================
__global__ __launch_bounds__(64) void ball2_kernel(const float* __restrict__ new_xyz1,
                                                   const float* __restrict__ new_xyz2,
                                                   int* __restrict__ idx2, float r2)
{
    const int s = blockIdx.x, b = blockIdx.y;
    const int lane = threadIdx.x;
    const float* pb = new_xyz1 + (size_t)b*N2*3;
    const float* cp = new_xyz2 + ((size_t)b*NP2 + s)*3;
    float cx = cp[0], cy = cp[1], cz = cp[2];
    float snew = sumsq3(cx,cy,cz);
    int* out = idx2 + ((size_t)b*NP2 + s)*NS2;
    int cnt = 0, first = 0;
    for (int ch = 0; ch < N2/64; ++ch) {
        int n = ch*64 + lane;
        float x = pb[n*3], y = pb[n*3+1], z = pb[n*3+2];
        float sx  = sumsq3(x,y,z);
        float dt  = dot3(cx,cy,cz,x,y,z);
        float sqr = fsub(fadd(snew, sx), fmul(2.0f, dt));
        bool inb = !(sqr > r2);
        unsigned long long mask = __ballot(inb);
        if (mask) {
            if (cnt == 0) first = ch*64 + (int)(__ffsll((unsigned long long)mask) - 1);
            if (inb) {
                int pos = cnt + (int)__popcll(mask & ((1ull << lane) - 1ull));
                if (pos < NS2) out[pos] = n;
            }
            cnt += (int)__popcll(mask);
            if (cnt >= NS2) break;
        }
    }
    int c = cnt < NS2 ? cnt : NS2;
    if (lane >= c) out[lane] = first;
}

// =====================  SA1 MLP (6->64->64->128) + maxpool over 32  =====================
// v7: lane=sample, weights wave-uniform (scalar s_load), per-lane activations
// in VGPRs, layer hand-off via conflict-free h[o][lane] LDS (no barriers:
// each lane touches only its own column). One wave = 2 centroids (2x32).
__global__ __launch_bounds__(64, 2) void mlp1_kernel(const float* __restrict__ xyz,
    const float* __restrict__ new_xyz1, const int* __restrict__ idx1,
    const float* __restrict__ W1, const float* __restrict__ B1,
    const float* __restrict__ W2, const float* __restrict__ B2,
    const float* __restrict__ W3, const float* __restrict__ B3,
    float* __restrict__ l1_points)
{
    const int b = blockIdx.y;
    const int lane = threadIdx.x;
    const int s = blockIdx.x*2 + (lane >> 5);
    const int k = lane & 31;                   // sample within centroid
    __shared__ float hbuf[64][64];             // 16 KB, [out][lane]

    const float* xb = xyz + (size_t)b*6*N1;
    const int n = idx1[((size_t)b*NP1 + s)*NS1 + k];
    const float* cp = new_xyz1 + ((size_t)b*NP1 + s)*3;

    float a[6];
    a[0] = xb[n]        - cp[0];
    a[1] = xb[N1 + n]   - cp[1];
    a[2] = xb[2*N1 + n] - cp[2];
    a[3] = xb[3*N1 + n];
    a[4] = xb[4*N1 + n];
    a[5] = xb[5*N1 + n];

    // L1: 6 -> 64
    for (int o = 0; o < 64; ++o) {
        const float* w = &W1[o*6];
        float acc = 0.f;
#pragma unroll
        for (int j = 0; j < 6; ++j) acc = fmaf(a[j], w[j], acc);
        hbuf[o][lane] = fmaxf(acc + B1[o], 0.f);
    }
    float h[64];
#pragma unroll
    for (int j = 0; j < 64; ++j) h[j] = hbuf[j][lane];

    // L2: 64 -> 64
    for (int o = 0; o < 64; ++o) {
        const float* w = &W2[o*64];
        float a0=0.f, a1=0.f, a2=0.f, a3=0.f;
#pragma unroll
        for (int q = 0; q < 16; ++q) {
            a0 = fmaf(h[q*4+0], w[q*4+0], a0);
            a1 = fmaf(h[q*4+1], w[q*4+1], a1);
            a2 = fmaf(h[q*4+2], w[q*4+2], a2);
            a3 = fmaf(h[q*4+3], w[q*4+3], a3);
        }
        hbuf[o][lane] = fmaxf(((a0+a1)+(a2+a3)) + B2[o], 0.f);
    }
#pragma unroll
    for (int j = 0; j < 64; ++j) h[j] = hbuf[j][lane];

    // L3: 64 -> 128, max over the 32 samples of each half-wave
    float* op = l1_points + ((size_t)b*NP1 + s)*128;
    for (int o = 0; o < 128; ++o) {
        const float* w = &W3[o*64];
        float a0=0.f, a1=0.f, a2=0.f, a3=0.f;
#pragma unroll
        for (int q = 0; q < 16; ++q) {
            a0 = fmaf(h[q*4+0], w[q*4+0], a0);
            a1 = fmaf(h[q*4+1], w[q*4+1], a1);
            a2 = fmaf(h[q*4+2], w[q*4+2], a2);
            a3 = fmaf(h[q*4+3], w[q*4+3], a3);
        }
        float v = fmaxf(((a0+a1)+(a2+a3)) + B3[o], 0.f);
        v = fmaxf(v, __shfl_xor(v, 1, 64));
        v = fmaxf(v, __shfl_xor(v, 2, 64));
        v = fmaxf(v, __shfl_xor(v, 4, 64));
        v = fmaxf(v, __shfl_xor(v, 8, 64));
        v = fmaxf(v, __shfl_xor(v, 16, 64));
        if (k == 0) op[o] = v;      // lanes 0 and 32 store their centroid
    }
}

// =====================  SA2 MLP (131->128->128->285) + maxpool over 64  =====================
// v7: lane=sample (NS2=64 = wave width). Activations in VGPRs, weights via
// wave-uniform scalar loads (1 v_fmac per MAC, 4 accumulators for ILP),
// h[o][lane] LDS ping-pong (no barriers), butterfly-max epilogue.
__global__ __launch_bounds__(64, 1) void mlp2_kernel(
    const float* __restrict__ new_xyz1, const float* __restrict__ l1_points,
    const float* __restrict__ new_xyz2, const int* __restrict__ idx2,
    const float* __restrict__ W1, const float* __restrict__ B1,
    const float* __restrict__ W2, const float* __restrict__ B2,
    const float* __restrict__ W3, const float* __restrict__ B3,
    float* __restrict__ out1)
{
    const int s = blockIdx.x, b = blockIdx.y;
    const int k = threadIdx.x;                 // lane = sample
    __shared__ float hbuf[128][64];            // 32 KB, [out][lane]

    const int n = idx2[((size_t)b*NP2 + s)*NS2 + k];
    const float* cp = new_xyz2 + ((size_t)b*NP2 + s)*3;

    float a[131];
    {
        const float* fp = l1_points + ((size_t)b*N2 + n)*128;
#pragma unroll
        for (int q = 0; q < 32; ++q) {
            float4 v = *(const float4*)&fp[q*4];
            a[3+q*4+0]=v.x; a[3+q*4+1]=v.y; a[3+q*4+2]=v.z; a[3+q*4+3]=v.w;
        }
        const float* xp = new_xyz1 + ((size_t)b*N2 + n)*3;
        a[0] = xp[0]-cp[0]; a[1] = xp[1]-cp[1]; a[2] = xp[2]-cp[2];
    }

    // L1: 131 -> 128   (W1 cols: 0..2 = rel coords, 3..130 = feats)
    for (int o = 0; o < 128; ++o) {
        const float* w = &W1[o*131];
        float a0=0.f, a1=0.f, a2=0.f, a3=0.f;
#pragma unroll
        for (int q = 0; q < 32; ++q) {
            a0 = fmaf(a[q*4+0], w[q*4+0], a0);
            a1 = fmaf(a[q*4+1], w[q*4+1], a1);
            a2 = fmaf(a[q*4+2], w[q*4+2], a2);
            a3 = fmaf(a[q*4+3], w[q*4+3], a3);
        }
        a0 = fmaf(a[128], w[128], a0);
        a1 = fmaf(a[129], w[129], a1);
        a2 = fmaf(a[130], w[130], a2);
        hbuf[o][k] = fmaxf(((a0+a1)+(a2+a3)) + B1[o], 0.f);
    }
    float h[128];
#pragma unroll
    for (int j = 0; j < 128; ++j) h[j] = hbuf[j][k];

    // L2: 128 -> 128
    for (int o = 0; o < 128; ++o) {
        const float* w = &W2[o*128];
        float a0=0.f, a1=0.f, a2=0.f, a3=0.f;
#pragma unroll
        for (int q = 0; q < 32; ++q) {
            a0 = fmaf(h[q*4+0], w[q*4+0], a0);
            a1 = fmaf(h[q*4+1], w[q*4+1], a1);
            a2 = fmaf(h[q*4+2], w[q*4+2], a2);
            a3 = fmaf(h[q*4+3], w[q*4+3], a3);
        }
        hbuf[o][k] = fmaxf(((a0+a1)+(a2+a3)) + B2[o], 0.f);
    }
#pragma unroll
    for (int j = 0; j < 128; ++j) h[j] = hbuf[j][k];

    // L3: 128 -> 285, butterfly-max over the 64 samples, lane 0 stores
    float* op = out1 + ((size_t)b*NP2 + s)*285;
    for (int o = 0; o < 285; ++o) {
        const float* w = &W3[o*128];
        float a0=0.f, a1=0.f, a2=0.f, a3=0.f;
#pragma unroll
        for (int q = 0; q < 32; ++q) {
            a0 = fmaf(h[q*4+0], w[q*4+0], a0);
            a1 = fmaf(h[q*4+1], w[q*4+1], a1);
            a2 = fmaf(h[q*4+2], w[q*4+2], a2);
            a3 = fmaf(h[q*4+3], w[q*4+3], a3);
        }
        float v = fmaxf(((a0+a1)+(a2+a3)) + B3[o], 0.f);
        v = fmaxf(v, __shfl_xor(v, 1, 64));
        v = fmaxf(v, __shfl_xor(v, 2, 64));
        v = fmaxf(v, __shfl_xor(v, 4, 64));
        v = fmaxf(v, __shfl_xor(v, 8, 64));
        v = fmaxf(v, __shfl_xor(v, 16, 64));
        v = fmaxf(v, __shfl_xor(v, 32, 64));
        if (k == 0) op[o] = v;
    }
}

extern "C" void kernel_launch(void* const* d_in, const int* in_sizes, int n_in,
                              void* d_out, int out_size, void* d_ws, size_t ws_size,
                              hipStream_t stream)
{
    (void)in_sizes; (void)n_in; (void)out_size; (void)ws_size;
    const float* xyz  = (const float*)d_in[0];
    const float* s1w1 = (const float*)d_in[1];  const float* s1b1 = (const float*)d_in[2];
    const float* s1w2 = (const float*)d_in[3];  const float* s1b2 = (const float*)d_in[4];
    const float* s1w3 = (const float*)d_in[5];  const float* s1b3 = (const float*)d_in[6];
    const float* s2w1 = (const float*)d_in[7];  const float* s2b1 = (const float*)d_in[8];
    const float* s2w2 = (const float*)d_in[9];  const float* s2b2 = (const float*)d_in[10];
    const float* s2w3 = (const float*)d_in[11]; const float* s2b3 = (const float*)d_in[12];

    float* ws        = (float*)d_ws;
    float* new_xyz1  = ws;                  // 8*512*3   = 12288 f
    float* new_xyz2  = ws + 12288;          // 8*256*3   = 6144 f
    float* l1_points = ws + 18432;          // 8*512*128 = 524288 f
    int*   idx1      = (int*)(ws + 542720); // 8*512*32  = 131072 i
    int*   idx2      = idx1 + 131072;       // 8*256*64  = 131072 i
    // fps1 exchange slots: 8 batches x 2 parities x 16 blocks u64 (2 KB).
    unsigned long long* bests = (unsigned long long*)(ws + 804864);

    float* out0 = (float*)d_out;            // (8,3,256)
    float* out1 = out0 + 8*3*256;           // (8,256,285)

    const float r2a = (float)(0.025*0.025);
    const float r2b = (float)(0.05*0.05);

    fps1_kernel <<<dim3(FPS1_M*8), dim3(FPS1_TB), 0, stream>>>(xyz, new_xyz1, bests);
    ball1_kernel<<<dim3(NP1, 8),   dim3(64),      0, stream>>>(xyz, new_xyz1, idx1, r2a);
    mlp1_kernel <<<dim3(NP1/2, 8), dim3(64),      0, stream>>>(xyz, new_xyz1, idx1,
                    s1w1,s1b1,s1w2,s1b2,s1w3,s1b3, l1_points);
    fps2_kernel <<<dim3(8),        dim3(64),      0, stream>>>(new_xyz1, new_xyz2, out0);
    ball2_kernel<<<dim3(NP2, 8),   dim3(64),      0, stream>>>(new_xyz1, new_xyz2, idx2, r2b);
    mlp2_kernel <<<dim3(NP2, 8),   dim3(64),      0, stream>>>(new_xyz1, l1_points, new_xyz2, idx2,
                    s2w1,s2b1,s2w2,s2b2,s2w3,s2b3, out1);
}

// Round 8
// 2896.877 us; speedup vs baseline: 1.1960x; 1.1960x over previous
//
#include <hip/hip_runtime.h>

#define N1 32768
#define NP1 512
#define NS1 32
#define N2 512
#define NP2 256
#define NS2 64

// ---- exact-rounding helpers: replicate reference op-by-op (NO fma/contract) ----
__device__ __forceinline__ float fadd(float a, float b){ return __fadd_rn(a,b); }
__device__ __forceinline__ float fmul(float a, float b){ return __fmul_rn(a,b); }
__device__ __forceinline__ float fsub(float a, float b){ return __fsub_rn(a,b); }

__device__ __forceinline__ float dist3(float px,float py,float pz,float cx,float cy,float cz){
    float dx = fsub(px,cx), dy = fsub(py,cy), dz = fsub(pz,cz);
    return fadd(fadd(fmul(dx,dx), fmul(dy,dy)), fmul(dz,dz));
}
__device__ __forceinline__ float sumsq3(float x,float y,float z){
    return fadd(fadd(fmul(x,x), fmul(y,y)), fmul(z,z));
}
__device__ __forceinline__ float dot3(float ax,float ay,float az,float bx,float by,float bz){
    return fadd(fadd(fmul(ax,bx), fmul(ay,by)), fmul(az,bz));
}

__device__ __forceinline__ unsigned long long shflmax64(unsigned long long k, int off){
    unsigned long long o = __shfl_xor(k, off, 64);
    return o > k ? o : k;
}

// =====================  FPS over 32768 pts, 512 picks  =====================
// v8 = R6 exactly (2-D grid, batch-major dispatch adjacency — R7's 1-D
// swizzle regressed catastrophically). 16 blocks/batch, 256 thr, 8 pts/thread.
#define FPS1_M  16
#define FPS1_TB 256

__global__ __launch_bounds__(FPS1_TB) void fps1_kernel(const float* __restrict__ xyz,
                                                       float* __restrict__ new_xyz1,
                                                       unsigned long long* __restrict__ bests)
{
    const int m = blockIdx.x;          // chunk within batch
    const int b = blockIdx.y;          // batch
    const int t = threadIdx.x;
    const int lane = t & 63;
    const int wid  = t >> 6;           // 4 waves
    const float* xb = xyz + (size_t)b * 6 * N1;

    __shared__ unsigned long long wb[4];
    __shared__ float cw[4];

    const int base = m * (N1 / FPS1_M);   // 2048-pt chunk
    float px[8], py[8], pz[8], dd[8];
#pragma unroll
    for (int j = 0; j < 8; ++j) {
        int n = base + t + j * FPS1_TB;
        px[j] = xb[n];
        py[j] = xb[N1 + n];
        pz[j] = xb[2*N1 + n];
        dd[j] = 1e10f;
    }

    float cx = xb[0], cy = xb[N1], cz = xb[2*N1];   // first pick = index 0

    for (int s = 0; s < NP1; ++s) {
        if (m == 0 && t == 0) {
            float* o = new_xyz1 + ((size_t)b*NP1 + s)*3;
            o[0] = cx; o[1] = cy; o[2] = cz;
        }
        if (s == NP1 - 1) break;

        // update min-dists, in-thread argmax (ascending n -> first-max kept)
        float bv = -1.0f; int bi = base + t;
#pragma unroll
        for (int j = 0; j < 8; ++j) {
            float d  = dist3(px[j],py[j],pz[j],cx,cy,cz);
            float nd = fminf(dd[j], d);
            dd[j] = nd;
            if (nd > bv) { bv = nd; bi = base + t + j*FPS1_TB; }
        }
        // packed key: float bits order-isomorphic (dist>=0); tie -> min index
        unsigned long long pk = ((unsigned long long)__float_as_uint(bv) << 15)
                              | (unsigned long long)(32767 - bi);
        pk = shflmax64(pk, 1);  pk = shflmax64(pk, 2);  pk = shflmax64(pk, 4);
        pk = shflmax64(pk, 8);  pk = shflmax64(pk, 16); pk = shflmax64(pk, 32);
        if (lane == 0) wb[wid] = pk;
        __syncthreads();

        if (wid == 0) {
            unsigned long long k4 = (lane < 4) ? wb[lane] : 0ull;
            k4 = shflmax64(k4, 1); k4 = shflmax64(k4, 2);
            unsigned long long* slotPar = bests + ((size_t)b*2 + (s & 1))*FPS1_M;
            if (lane == 0)
                __hip_atomic_store(slotPar + m, (k4 << 10) | (unsigned long long)s,
                                   __ATOMIC_RELAXED, __HIP_MEMORY_SCOPE_AGENT);
            // parallel poll: lane q watches slot q; speculative centroid load
            unsigned long long myv = 0; bool done = (lane >= FPS1_M);
            float ccx = 0.f, ccy = 0.f, ccz = 0.f;
            while (__ballot(done) != 0xFFFFFFFFFFFFFFFFull) {
                if (!done) {
                    unsigned long long v = __hip_atomic_load(slotPar + lane,
                                             __ATOMIC_RELAXED, __HIP_MEMORY_SCOPE_AGENT);
                    if ((unsigned)(v & 1023ull) == (unsigned)s) {
                        done = true; myv = v;
                        int idx = 32767 - (int)((v >> 10) & 0x7fffull);
                        ccx = xb[idx]; ccy = xb[N1 + idx]; ccz = xb[2*N1 + idx];
                    }
                }
            }
            unsigned long long w = myv;
            w = shflmax64(w, 1); w = shflmax64(w, 2); w = shflmax64(w, 4); w = shflmax64(w, 8);
            int wl = (int)__ffsll(__ballot(myv == w)) - 1;   // keys unique; lanes>=16 have 0
            float ncx = __shfl(ccx, wl, 64);
            float ncy = __shfl(ccy, wl, 64);
            float ncz = __shfl(ccz, wl, 64);
            if (lane == 0) { cw[0] = ncx; cw[1] = ncy; cw[2] = ncz; }
        }
        __syncthreads();
        cx = cw[0]; cy = cw[1]; cz = cw[2];
    }
}

// =====================  FPS over 512 pts, 256 picks: 1 wave/batch  =====================
__global__ __launch_bounds__(64) void fps2_kernel(const float* __restrict__ new_xyz1,
                                                  float* __restrict__ new_xyz2,
                                                  float* __restrict__ out0)
{
    const int b = blockIdx.x;
    const int t = threadIdx.x;
    __shared__ float c3[N2*3];
    const float* src = new_xyz1 + (size_t)b*N2*3;
    for (int e = t; e < N2*3; e += 64) c3[e] = src[e];
    __syncthreads();

    float px[8], py[8], pz[8], dd[8];
#pragma unroll
    for (int j = 0; j < 8; ++j) {
        int n = t + j*64;
        px[j] = c3[n*3]; py[j] = c3[n*3+1]; pz[j] = c3[n*3+2];
        dd[j] = 1e10f;
    }
    int cur = 0;
    for (int s = 0; s < NP2; ++s) {
        float cx = c3[cur*3], cy = c3[cur*3+1], cz = c3[cur*3+2];
        if (t == 0) {
            float* o = new_xyz2 + ((size_t)b*NP2 + s)*3;
            o[0]=cx; o[1]=cy; o[2]=cz;
            out0[b*3*NP2 + s]         = cx;   // l2_xyz transposed (8,3,256)
            out0[b*3*NP2 + NP2 + s]   = cy;
            out0[b*3*NP2 + 2*NP2 + s] = cz;
        }
        float bv = -1.0f; int bi = 0x7fffffff;
#pragma unroll
        for (int j = 0; j < 8; ++j) {
            float d  = dist3(px[j],py[j],pz[j],cx,cy,cz);
            float nd = fminf(dd[j], d);
            dd[j] = nd;
            int n = t + j*64;
            if (nd > bv) { bv = nd; bi = n; }
        }
#pragma unroll
        for (int m = 1; m < 64; m <<= 1) {
            float ov = __shfl_xor(bv, m, 64);
            int   oi = __shfl_xor(bi, m, 64);
            if (ov > bv || (ov == bv && oi < bi)) { bv = ov; bi = oi; }
        }
        cur = bi;
    }
}

// =====================  ball query 1: 1 wave per centroid  =====================
__global__ __launch_bounds__(64) void ball1_kernel(const float* __restrict__ xyz,
                                                   const float* __restrict__ new_xyz1,
                                                   int* __restrict__ idx1, float r2)
{
    const int s = blockIdx.x, b = blockIdx.y;
    const int lane = threadIdx.x;
    const float* xb = xyz + (size_t)b*6*N1;
    const float* cp = new_xyz1 + ((size_t)b*NP1 + s)*3;
    float cx = cp[0], cy = cp[1], cz = cp[2];
    float snew = sumsq3(cx,cy,cz);
    int* out = idx1 + ((size_t)b*NP1 + s)*NS1;
    int cnt = 0, first = 0;
    for (int ch = 0; ch < N1/64; ++ch) {
        int n = ch*64 + lane;
        float x = xb[n], y = xb[N1+n], z = xb[2*N1+n];
        float sx  = sumsq3(x,y,z);
        float dt  = dot3(cx,cy,cz,x,y,z);
        float sqr = fsub(fadd(snew, sx), fmul(2.0f, dt));   // (|c|^2+|p|^2) - 2*dot
        bool inb = !(sqr > r2);
        unsigned long long mask = __ballot(inb);
        if (mask) {
            if (cnt == 0) first = ch*64 + (int)(__ffsll((unsigned long long)mask) - 1);
            if (inb) {
                int pos = cnt + (int)__popcll(mask & ((1ull << lane) - 1ull));
                if (pos < NS1) out[pos] = n;
            }
            cnt += (int)__popcll(mask);
            if (cnt >= NS1) break;
        }
    }
    int c = cnt < NS1 ? cnt : NS1;
    if (lane < NS1 && lane >= c) out[lane] = first;
}

// =====================  ball query 2  =====================
__global__ __launch_bounds__(64) void ball2_kernel(const float* __restrict__ new_xyz1,
                                                   const float* __restrict__ new_xyz2,
                                                   int* __restrict__ idx2, float r2)
{
    const int s = blockIdx.x, b = blockIdx.y;
    const int lane = threadIdx.x;
    const float* pb = new_xyz1 + (size_t)b*N2*3;
    const float* cp = new_xyz2 + ((size_t)b*NP2 + s)*3;
    float cx = cp[0], cy = cp[1], cz = cp[2];
    float snew = sumsq3(cx,cy,cz);
    int* out = idx2 + ((size_t)b*NP2 + s)*NS2;
    int cnt = 0, first = 0;
    for (int ch = 0; ch < N2/64; ++ch) {
        int n = ch*64 + lane;
        float x = pb[n*3], y = pb[n*3+1], z = pb[n*3+2];
        float sx  = sumsq3(x,y,z);
        float dt  = dot3(cx,cy,cz,x,y,z);
        float sqr = fsub(fadd(snew, sx), fmul(2.0f, dt));
        bool inb = !(sqr > r2);
        unsigned long long mask = __ballot(inb);
        if (mask) {
            if (cnt == 0) first = ch*64 + (int)(__ffsll((unsigned long long)mask) - 1);
            if (inb) {
                int pos = cnt + (int)__popcll(mask & ((1ull << lane) - 1ull));
                if (pos < NS2) out[pos] = n;
            }
            cnt += (int)__popcll(mask);
            if (cnt >= NS2) break;
        }
    }
    int c = cnt < NS2 ? cnt : NS2;
    if (lane >= c) out[lane] = first;
}

// =====================  SA1 MLP (6->64->64->128) + maxpool over 32  =====================
// R6 version (known-good): float4 LDS reads in L2/L3.
__global__ __launch_bounds__(256) void mlp1_kernel(const float* __restrict__ xyz,
    const float* __restrict__ new_xyz1, const int* __restrict__ idx1,
    const float* __restrict__ W1, const float* __restrict__ B1,
    const float* __restrict__ W2, const float* __restrict__ B2,
    const float* __restrict__ W3, const float* __restrict__ B3,
    float* __restrict__ l1_points)
{
    const int s = blockIdx.x, b = blockIdx.y;
    const int t = threadIdx.x;
    const float* xb = xyz + (size_t)b*6*N1;
    __shared__ __align__(16) float inb_[NS1][6];
    __shared__ __align__(16) float h1_[NS1][64];
    __shared__ __align__(16) float h2_[NS1][64];
    __shared__ __align__(16) float red_[2][128];
    __shared__ int sidx[NS1];

    const float* cp = new_xyz1 + ((size_t)b*NP1 + s)*3;
    float c0 = cp[0], c1 = cp[1], c2 = cp[2];
    if (t < NS1) sidx[t] = idx1[((size_t)b*NP1+s)*NS1 + t];
    __syncthreads();
    if (t < NS1*6) {
        int k = t / 6, c = t % 6;
        int n = sidx[k];
        float v = xb[(size_t)c*N1 + n];
        if (c == 0) v -= c0; else if (c == 1) v -= c1; else if (c == 2) v -= c2;
        inb_[k][c] = v;
    }
    __syncthreads();
    {   // L1
        int o = t & 63, kg = t >> 6;
        float w[6];
#pragma unroll
        for (int c = 0; c < 6; ++c) w[c] = W1[o*6+c];
        float bias = B1[o];
#pragma unroll
        for (int kk = 0; kk < 8; ++kk) {
            int k = kg*8 + kk;
            float a = 0.f;
#pragma unroll
            for (int c = 0; c < 6; ++c) a = fmaf(inb_[k][c], w[c], a);
            h1_[k][o] = fmaxf(a + bias, 0.f);
        }
    }
    __syncthreads();
    {   // L2: 64 -> 64
        int o = t & 63, kg = t >> 6;
        float acc[8] = {};
        for (int ch = 0; ch < 8; ++ch) {
            const float4 wa = *(const float4*)&W2[o*64 + ch*8];
            const float4 wbv = *(const float4*)&W2[o*64 + ch*8 + 4];
#pragma unroll
            for (int kk = 0; kk < 8; ++kk) {
                int k = kg*8+kk;
                const float4 a0 = *(const float4*)&h1_[k][ch*8];
                const float4 a1 = *(const float4*)&h1_[k][ch*8+4];
                acc[kk] = fmaf(a0.x, wa.x, acc[kk]);
                acc[kk] = fmaf(a0.y, wa.y, acc[kk]);
                acc[kk] = fmaf(a0.z, wa.z, acc[kk]);
                acc[kk] = fmaf(a0.w, wa.w, acc[kk]);
                acc[kk] = fmaf(a1.x, wbv.x, acc[kk]);
                acc[kk] = fmaf(a1.y, wbv.y, acc[kk]);
                acc[kk] = fmaf(a1.z, wbv.z, acc[kk]);
                acc[kk] = fmaf(a1.w, wbv.w, acc[kk]);
            }
        }
        float bias = B2[o];
#pragma unroll
        for (int kk = 0; kk < 8; ++kk) h2_[kg*8+kk][o] = fmaxf(acc[kk] + bias, 0.f);
    }
    __syncthreads();
    {   // L3: 64 -> 128 + max over samples
        int o = t & 127, kg = t >> 7;
        float acc[16] = {};
        for (int ch = 0; ch < 8; ++ch) {
            const float4 wa = *(const float4*)&W3[o*64 + ch*8];
            const float4 wbv = *(const float4*)&W3[o*64 + ch*8 + 4];
#pragma unroll
            for (int kk = 0; kk < 16; ++kk) {
                int k = kg*16+kk;
                const float4 a0 = *(const float4*)&h2_[k][ch*8];
                const float4 a1 = *(const float4*)&h2_[k][ch*8+4];
                acc[kk] = fmaf(a0.x, wa.x, acc[kk]);
                acc[kk] = fmaf(a0.y, wa.y, acc[kk]);
                acc[kk] = fmaf(a0.z, wa.z, acc[kk]);
                acc[kk] = fmaf(a0.w, wa.w, acc[kk]);
                acc[kk] = fmaf(a1.x, wbv.x, acc[kk]);
                acc[kk] = fmaf(a1.y, wbv.y, acc[kk]);
                acc[kk] = fmaf(a1.z, wbv.z, acc[kk]);
                acc[kk] = fmaf(a1.w, wbv.w, acc[kk]);
            }
        }
        float bias = B3[o];
        float m = -1e30f;
#pragma unroll
        for (int kk = 0; kk < 16; ++kk) m = fmaxf(m, fmaxf(acc[kk] + bias, 0.f));
        red_[kg][o] = m;
    }
    __syncthreads();
    if (t < 128) {
        float m = fmaxf(red_[0][t], red_[1][t]);
        l1_points[((size_t)b*NP1+s)*128 + t] = m;   // (b, n, 128) layout
    }
}

// =====================  SA2 MLP (131->128->128->285) + maxpool over 64  =====================
// v8: 2 waves/block, lane=sample, FEATURE-SPLIT across waves.
// Wave w owns input-feature half; per-lane regs: a_half(<=67) + h_half(64)
// ~= 95 VGPR (v7's 259-reg scratch bug fixed). Weights are wave-uniform ->
// scalar s_loads feeding v_fmac (1 VALU instr/MAC). Per layer: phase A =
// partials for the OTHER wave's output half into part[][] (lane-stride-1 LDS,
// conflict-free); phase B = finalize own half (own dot + partial + bias +
// ReLU) writing finals back into part[][]; reload own feature half into regs.
// L3 (285 outs) chunked at 128 reusing part; butterfly-max epilogue.
__global__ __launch_bounds__(128, 1) void mlp2_kernel(
    const float* __restrict__ new_xyz1, const float* __restrict__ l1_points,
    const float* __restrict__ new_xyz2, const int* __restrict__ idx2,
    const float* __restrict__ W1, const float* __restrict__ B1,
    const float* __restrict__ W2, const float* __restrict__ B2,
    const float* __restrict__ W3, const float* __restrict__ B3,
    float* __restrict__ out1)
{
    const int s = blockIdx.x, b = blockIdx.y;
    const int k = threadIdx.x & 63;    // lane = sample
    const int w = threadIdx.x >> 6;    // wave = feature half
    __shared__ float part[128][64];    // 32 KB partial/final exchange

    const int n = idx2[((size_t)b*NP2 + s)*NS2 + k];
    const float* fp = l1_points + ((size_t)b*N2 + n)*128;

    // ---- L1: 131 -> 128. W1 columns: wave0 owns c in [0,67) = 3 coords +
    // feats 0..63; wave1 owns c in [67,131) = feats 64..127.
    {
        float a[67];
        if (w == 0) {
            const float* xp = new_xyz1 + ((size_t)b*N2 + n)*3;
            const float* cp = new_xyz2 + ((size_t)b*NP2 + s)*3;
            a[0] = xp[0]-cp[0]; a[1] = xp[1]-cp[1]; a[2] = xp[2]-cp[2];
#pragma unroll
            for (int q = 0; q < 16; ++q) {
                float4 v = *(const float4*)&fp[q*4];
                a[3+q*4]=v.x; a[4+q*4]=v.y; a[5+q*4]=v.z; a[6+q*4]=v.w;
            }
        } else {
#pragma unroll
            for (int q = 0; q < 16; ++q) {
                float4 v = *(const float4*)&fp[64 + q*4];
                a[q*4]=v.x; a[1+q*4]=v.y; a[2+q*4]=v.z; a[3+q*4]=v.w;
            }
        }
        auto dot1 = [&](const float* wp) -> float {
            float p0=0.f,p1=0.f,p2=0.f,p3=0.f;
            if (w == 0) {
#pragma unroll
                for (int q = 0; q < 16; ++q) {
                    p0 = fmaf(a[3+q*4], wp[3+q*4], p0);
                    p1 = fmaf(a[4+q*4], wp[4+q*4], p1);
                    p2 = fmaf(a[5+q*4], wp[5+q*4], p2);
                    p3 = fmaf(a[6+q*4], wp[6+q*4], p3);
                }
                p0 = fmaf(a[0], wp[0], p0);
                p1 = fmaf(a[1], wp[1], p1);
                p2 = fmaf(a[2], wp[2], p2);
            } else {
#pragma unroll
                for (int q = 0; q < 16; ++q) {
                    p0 = fmaf(a[q*4],   wp[67+q*4], p0);
                    p1 = fmaf(a[1+q*4], wp[68+q*4], p1);
                    p2 = fmaf(a[2+q*4], wp[69+q*4], p2);
                    p3 = fmaf(a[3+q*4], wp[70+q*4], p3);
                }
            }
            return (p0+p1)+(p2+p3);
        };
        // phase A: partials for the other wave's outputs
        {
            const int oA = w ? 0 : 64;
            for (int i = 0; i < 64; ++i) {
                int o = oA + i;
                part[o][k] = dot1(&W1[(size_t)o*131]);
            }
        }
        __syncthreads();
        // phase B: finalize own outputs -> final value into part[o][k]
        {
            const int oB = w ? 64 : 0;
            for (int i = 0; i < 64; ++i) {
                int o = oB + i;
                float v = dot1(&W1[(size_t)o*131]) + part[o][k] + B1[o];
                part[o][k] = fmaxf(v, 0.f);
            }
        }
        __syncthreads();
    }
    // reload own feature half (wave w owns features [w*64, w*64+64))
    float h[64];
#pragma unroll
    for (int j = 0; j < 64; ++j) h[j] = part[w*64 + j][k];
    __syncthreads();

    auto dot2 = [&](const float* wp) -> float {   // wp = weight row base; own cols at +w*64
        float p0=0.f,p1=0.f,p2=0.f,p3=0.f;
        const float* wq = wp + w*64;
#pragma unroll
        for (int q = 0; q < 16; ++q) {
            p0 = fmaf(h[q*4],   wq[q*4],   p0);
            p1 = fmaf(h[1+q*4], wq[1+q*4], p1);
            p2 = fmaf(h[2+q*4], wq[2+q*4], p2);
            p3 = fmaf(h[3+q*4], wq[3+q*4], p3);
        }
        return (p0+p1)+(p2+p3);
    };

    // ---- L2: 128 -> 128 ----
    {
        const int oA = w ? 0 : 64;
        for (int i = 0; i < 64; ++i) {
            int o = oA + i;
            part[o][k] = dot2(&W2[(size_t)o*128]);
        }
        __syncthreads();
        const int oB = w ? 64 : 0;
        for (int i = 0; i < 64; ++i) {
            int o = oB + i;
            float v = dot2(&W2[(size_t)o*128]) + part[o][k] + B2[o];
            part[o][k] = fmaxf(v, 0.f);
        }
        __syncthreads();
    }
#pragma unroll
    for (int j = 0; j < 64; ++j) h[j] = part[w*64 + j][k];
    __syncthreads();

    // ---- L3: 128 -> 285, chunks of <=128, maxpool over 64 samples ----
    float* op = out1 + ((size_t)b*NP2 + s)*285;
    for (int C = 0; C < 285; C += 128) {
        const int L = (285 - C) < 128 ? (285 - C) : 128;
        const int half = (L + 1) >> 1;
        {   // phase A: partials for the other wave's rows
            const int lo = w ? 0 : half, hi = w ? half : L;
            for (int i = lo; i < hi; ++i)
                part[i][k] = dot2(&W3[(size_t)(C+i)*128]);
        }
        __syncthreads();
        {   // phase B: finalize own rows, butterfly-max, lane 0 stores
            const int lo = w ? half : 0, hi = w ? L : half;
            for (int i = lo; i < hi; ++i) {
                float v = dot2(&W3[(size_t)(C+i)*128]) + part[i][k] + B3[C+i];
                v = fmaxf(v, 0.f);
                v = fmaxf(v, __shfl_xor(v, 1, 64));
                v = fmaxf(v, __shfl_xor(v, 2, 64));
                v = fmaxf(v, __shfl_xor(v, 4, 64));
                v = fmaxf(v, __shfl_xor(v, 8, 64));
                v = fmaxf(v, __shfl_xor(v, 16, 64));
                v = fmaxf(v, __shfl_xor(v, 32, 64));
                if (k == 0) op[C+i] = v;
            }
        }
        __syncthreads();
    }
}

extern "C" void kernel_launch(void* const* d_in, const int* in_sizes, int n_in,
                              void* d_out, int out_size, void* d_ws, size_t ws_size,
                              hipStream_t stream)
{
    (void)in_sizes; (void)n_in; (void)out_size; (void)ws_size;
    const float* xyz  = (const float*)d_in[0];
    const float* s1w1 = (const float*)d_in[1];  const float* s1b1 = (const float*)d_in[2];
    const float* s1w2 = (const float*)d_in[3];  const float* s1b2 = (const float*)d_in[4];
    const float* s1w3 = (const float*)d_in[5];  const float* s1b3 = (const float*)d_in[6];
    const float* s2w1 = (const float*)d_in[7];  const float* s2b1 = (const float*)d_in[8];
    const float* s2w2 = (const float*)d_in[9];  const float* s2b2 = (const float*)d_in[10];
    const float* s2w3 = (const float*)d_in[11]; const float* s2b3 = (const float*)d_in[12];

    float* ws        = (float*)d_ws;
    float* new_xyz1  = ws;                  // 8*512*3   = 12288 f
    float* new_xyz2  = ws + 12288;          // 8*256*3   = 6144 f
    float* l1_points = ws + 18432;          // 8*512*128 = 524288 f
    int*   idx1      = (int*)(ws + 542720); // 8*512*32  = 131072 i
    int*   idx2      = idx1 + 131072;       // 8*256*64  = 131072 i
    // fps1 exchange slots: 8 batches x 2 parities x 16 blocks u64 (2 KB).
    unsigned long long* bests = (unsigned long long*)(ws + 804864);

    float* out0 = (float*)d_out;            // (8,3,256)
    float* out1 = out0 + 8*3*256;           // (8,256,285)

    const float r2a = (float)(0.025*0.025);
    const float r2b = (float)(0.05*0.05);

    fps1_kernel <<<dim3(FPS1_M, 8), dim3(FPS1_TB), 0, stream>>>(xyz, new_xyz1, bests);
    ball1_kernel<<<dim3(NP1, 8),    dim3(64),      0, stream>>>(xyz, new_xyz1, idx1, r2a);
    mlp1_kernel <<<dim3(NP1, 8),    dim3(256),     0, stream>>>(xyz, new_xyz1, idx1,
                    s1w1,s1b1,s1w2,s1b2,s1w3,s1b3, l1_points);
    fps2_kernel <<<dim3(8),         dim3(64),      0, stream>>>(new_xyz1, new_xyz2, out0);
    ball2_kernel<<<dim3(NP2, 8),    dim3(64),      0, stream>>>(new_xyz1, new_xyz2, idx2, r2b);
    mlp2_kernel <<<dim3(NP2, 8),    dim3(128),     0, stream>>>(new_xyz1, l1_points, new_xyz2, idx2,
                    s2w1,s2b1,s2w2,s2b2,s2w3,s2b3, out1);
}

// Round 9
// 1875.665 us; speedup vs baseline: 1.8471x; 1.5445x over previous
//
#include <hip/hip_runtime.h>

#define N1 32768
#define NP1 512
#define NS1 32
#define N2 512
#define NP2 256
#define NS2 64

// ---- exact-rounding helpers: replicate reference op-by-op (NO fma/contract) ----
__device__ __forceinline__ float fadd(float a, float b){ return __fadd_rn(a,b); }
__device__ __forceinline__ float fmul(float a, float b){ return __fmul_rn(a,b); }
__device__ __forceinline__ float fsub(float a, float b){ return __fsub_rn(a,b); }

__device__ __forceinline__ float dist3(float px,float py,float pz,float cx,float cy,float cz){
    float dx = fsub(px,cx), dy = fsub(py,cy), dz = fsub(pz,cz);
    return fadd(fadd(fmul(dx,dx), fmul(dy,dy)), fmul(dz,dz));
}
__device__ __forceinline__ float sumsq3(float x,float y,float z){
    return fadd(fadd(fmul(x,x), fmul(y,y)), fmul(z,z));
}
__device__ __forceinline__ float dot3(float ax,float ay,float az,float bx,float by,float bz){
    return fadd(fadd(fmul(ax,bx), fmul(ay,by)), fmul(az,bz));
}

__device__ __forceinline__ unsigned long long shflmax64(unsigned long long k, int off){
    unsigned long long o = __shfl_xor(k, off, 64);
    return o > k ? o : k;
}

// =====================  FPS over 32768 pts, 512 picks  =====================
// v9: barrier-free per-WAVE exchange. 16 blocks/batch x 4 waves = 64 waves;
// wave (m,w) owns 512 points and publishes its wave-reduced packed key to
// bests[b][s&1][m*4+w]. Every wave polls all 64 slots (lane q watches slot q,
// speculative centroid load on detect), 6-step u64 butterfly, coord shuffle.
// NO __syncthreads, NO LDS anywhere in the loop: the serial chain is
// compute -> butterfly -> store -> poll -> butterfly -> shfl.
// Safety: publish of step s+2 transitively requires every wave's completed
// read of step s (parity slots); ws is re-poisoned 0xAA before every launch
// so stale tags (682) never validate.
#define FPS1_M  16
#define FPS1_TB 256

__global__ __launch_bounds__(FPS1_TB) void fps1_kernel(const float* __restrict__ xyz,
                                                       float* __restrict__ new_xyz1,
                                                       unsigned long long* __restrict__ bests)
{
    const int m = blockIdx.x;          // chunk within batch
    const int b = blockIdx.y;          // batch
    const int t = threadIdx.x;
    const int lane = t & 63;
    const int wid  = t >> 6;           // 4 waves
    const int slot = m*4 + wid;        // 0..63 global wave slot
    const float* xb = xyz + (size_t)b * 6 * N1;

    const int base = m * (N1 / FPS1_M);   // 2048-pt chunk
    float px[8], py[8], pz[8], dd[8];
#pragma unroll
    for (int j = 0; j < 8; ++j) {
        int n = base + t + j * FPS1_TB;
        px[j] = xb[n];
        py[j] = xb[N1 + n];
        pz[j] = xb[2*N1 + n];
        dd[j] = 1e10f;
    }

    float cx = xb[0], cy = xb[N1], cz = xb[2*N1];   // first pick = index 0

    for (int s = 0; s < NP1; ++s) {
        if (m == 0 && t == 0) {
            float* o = new_xyz1 + ((size_t)b*NP1 + s)*3;
            o[0] = cx; o[1] = cy; o[2] = cz;
        }
        if (s == NP1 - 1) break;

        // update min-dists, in-thread argmax (ascending n -> first-max kept)
        float bv = -1.0f; int bi = base + t;
#pragma unroll
        for (int j = 0; j < 8; ++j) {
            float d  = dist3(px[j],py[j],pz[j],cx,cy,cz);
            float nd = fminf(dd[j], d);
            dd[j] = nd;
            if (nd > bv) { bv = nd; bi = base + t + j*FPS1_TB; }
        }
        // packed key: float bits order-isomorphic (dist>=0); tie -> min index
        unsigned long long pk = ((unsigned long long)__float_as_uint(bv) << 15)
                              | (unsigned long long)(32767 - bi);
        pk = shflmax64(pk, 1);  pk = shflmax64(pk, 2);  pk = shflmax64(pk, 4);
        pk = shflmax64(pk, 8);  pk = shflmax64(pk, 16); pk = shflmax64(pk, 32);

        unsigned long long* slotPar = bests + ((size_t)b*2 + (s & 1))*64;
        if (lane == 0)
            __hip_atomic_store(slotPar + slot, (pk << 10) | (unsigned long long)s,
                               __ATOMIC_RELAXED, __HIP_MEMORY_SCOPE_AGENT);

        // all 64 lanes poll: lane q watches slot q; speculative centroid load
        unsigned long long myv = 0; bool done = false;
        float ccx = 0.f, ccy = 0.f, ccz = 0.f;
        while (__ballot(done) != 0xFFFFFFFFFFFFFFFFull) {
            if (!done) {
                unsigned long long v = __hip_atomic_load(slotPar + lane,
                                         __ATOMIC_RELAXED, __HIP_MEMORY_SCOPE_AGENT);
                if ((unsigned)(v & 1023ull) == (unsigned)s) {
                    done = true; myv = v;
                    int idx = 32767 - (int)((v >> 10) & 0x7fffull);
                    ccx = xb[idx]; ccy = xb[N1 + idx]; ccz = xb[2*N1 + idx];
                }
            }
        }
        unsigned long long w = myv;
        w = shflmax64(w, 1);  w = shflmax64(w, 2);  w = shflmax64(w, 4);
        w = shflmax64(w, 8);  w = shflmax64(w, 16); w = shflmax64(w, 32);
        int wl = (int)__ffsll(__ballot(myv == w)) - 1;   // keys unique
        cx = __shfl(ccx, wl, 64);
        cy = __shfl(ccy, wl, 64);
        cz = __shfl(ccz, wl, 64);
    }
}

// =====================  FPS over 512 pts, 256 picks: 1 wave/batch  =====================
// v9: packed-u64 butterfly (single shflmax64 chain per step).
__global__ __launch_bounds__(64) void fps2_kernel(const float* __restrict__ new_xyz1,
                                                  float* __restrict__ new_xyz2,
                                                  float* __restrict__ out0)
{
    const int b = blockIdx.x;
    const int t = threadIdx.x;
    __shared__ float c3[N2*3];
    const float* src = new_xyz1 + (size_t)b*N2*3;
    for (int e = t; e < N2*3; e += 64) c3[e] = src[e];
    __syncthreads();

    float px[8], py[8], pz[8], dd[8];
#pragma unroll
    for (int j = 0; j < 8; ++j) {
        int n = t + j*64;
        px[j] = c3[n*3]; py[j] = c3[n*3+1]; pz[j] = c3[n*3+2];
        dd[j] = 1e10f;
    }
    int cur = 0;
    for (int s = 0; s < NP2; ++s) {
        float cx = c3[cur*3], cy = c3[cur*3+1], cz = c3[cur*3+2];
        if (t == 0) {
            float* o = new_xyz2 + ((size_t)b*NP2 + s)*3;
            o[0]=cx; o[1]=cy; o[2]=cz;
            out0[b*3*NP2 + s]         = cx;   // l2_xyz transposed (8,3,256)
            out0[b*3*NP2 + NP2 + s]   = cy;
            out0[b*3*NP2 + 2*NP2 + s] = cz;
        }
        float bv = -1.0f; int bi = 0;
#pragma unroll
        for (int j = 0; j < 8; ++j) {
            float d  = dist3(px[j],py[j],pz[j],cx,cy,cz);
            float nd = fminf(dd[j], d);
            dd[j] = nd;
            int n = t + j*64;
            if (nd > bv) { bv = nd; bi = n; }
        }
        unsigned long long pk = ((unsigned long long)__float_as_uint(bv) << 9)
                              | (unsigned long long)(511 - bi);
        pk = shflmax64(pk, 1);  pk = shflmax64(pk, 2);  pk = shflmax64(pk, 4);
        pk = shflmax64(pk, 8);  pk = shflmax64(pk, 16); pk = shflmax64(pk, 32);
        cur = 511 - (int)(pk & 511ull);
    }
}

// =====================  ball query 1: 1 wave per centroid  =====================
__global__ __launch_bounds__(64) void ball1_kernel(const float* __restrict__ xyz,
                                                   const float* __restrict__ new_xyz1,
                                                   int* __restrict__ idx1, float r2)
{
    const int s = blockIdx.x, b = blockIdx.y;
    const int lane = threadIdx.x;
    const float* xb = xyz + (size_t)b*6*N1;
    const float* cp = new_xyz1 + ((size_t)b*NP1 + s)*3;
    float cx = cp[0], cy = cp[1], cz = cp[2];
    float snew = sumsq3(cx,cy,cz);
    int* out = idx1 + ((size_t)b*NP1 + s)*NS1;
    int cnt = 0, first = 0;
    for (int ch = 0; ch < N1/64; ++ch) {
        int n = ch*64 + lane;
        float x = xb[n], y = xb[N1+n], z = xb[2*N1+n];
        float sx  = sumsq3(x,y,z);
        float dt  = dot3(cx,cy,cz,x,y,z);
        float sqr = fsub(fadd(snew, sx), fmul(2.0f, dt));   // (|c|^2+|p|^2) - 2*dot
        bool inb = !(sqr > r2);
        unsigned long long mask = __ballot(inb);
        if (mask) {
            if (cnt == 0) first = ch*64 + (int)(__ffsll((unsigned long long)mask) - 1);
            if (inb) {
                int pos = cnt + (int)__popcll(mask & ((1ull << lane) - 1ull));
                if (pos < NS1) out[pos] = n;
            }
            cnt += (int)__popcll(mask);
            if (cnt >= NS1) break;
        }
    }
    int c = cnt < NS1 ? cnt : NS1;
    if (lane < NS1 && lane >= c) out[lane] = first;
}

// =====================  ball query 2  =====================
__global__ __launch_bounds__(64) void ball2_kernel(const float* __restrict__ new_xyz1,
                                                   const float* __restrict__ new_xyz2,
                                                   int* __restrict__ idx2, float r2)
{
    const int s = blockIdx.x, b = blockIdx.y;
    const int lane = threadIdx.x;
    const float* pb = new_xyz1 + (size_t)b*N2*3;
    const float* cp = new_xyz2 + ((size_t)b*NP2 + s)*3;
    float cx = cp[0], cy = cp[1], cz = cp[2];
    float snew = sumsq3(cx,cy,cz);
    int* out = idx2 + ((size_t)b*NP2 + s)*NS2;
    int cnt = 0, first = 0;
    for (int ch = 0; ch < N2/64; ++ch) {
        int n = ch*64 + lane;
        float x = pb[n*3], y = pb[n*3+1], z = pb[n*3+2];
        float sx  = sumsq3(x,y,z);
        float dt  = dot3(cx,cy,cz,x,y,z);
        float sqr = fsub(fadd(snew, sx), fmul(2.0f, dt));
        bool inb = !(sqr > r2);
        unsigned long long mask = __ballot(inb);
        if (mask) {
            if (cnt == 0) first = ch*64 + (int)(__ffsll((unsigned long long)mask) - 1);
            if (inb) {
                int pos = cnt + (int)__popcll(mask & ((1ull << lane) - 1ull));
                if (pos < NS2) out[pos] = n;
            }
            cnt += (int)__popcll(mask);
            if (cnt >= NS2) break;
        }
    }
    int c = cnt < NS2 ? cnt : NS2;
    if (lane >= c) out[lane] = first;
}

// =====================  SA1 MLP (6->64->64->128) + maxpool over 32  =====================
// R6 version (known-good): float4 LDS reads in L2/L3.
__global__ __launch_bounds__(256) void mlp1_kernel(const float* __restrict__ xyz,
    const float* __restrict__ new_xyz1, const int* __restrict__ idx1,
    const float* __restrict__ W1, const float* __restrict__ B1,
    const float* __restrict__ W2, const float* __restrict__ B2,
    const float* __restrict__ W3, const float* __restrict__ B3,
    float* __restrict__ l1_points)
{
    const int s = blockIdx.x, b = blockIdx.y;
    const int t = threadIdx.x;
    const float* xb = xyz + (size_t)b*6*N1;
    __shared__ __align__(16) float inb_[NS1][6];
    __shared__ __align__(16) float h1_[NS1][64];
    __shared__ __align__(16) float h2_[NS1][64];
    __shared__ __align__(16) float red_[2][128];
    __shared__ int sidx[NS1];

    const float* cp = new_xyz1 + ((size_t)b*NP1 + s)*3;
    float c0 = cp[0], c1 = cp[1], c2 = cp[2];
    if (t < NS1) sidx[t] = idx1[((size_t)b*NP1+s)*NS1 + t];
    __syncthreads();
    if (t < NS1*6) {
        int k = t / 6, c = t % 6;
        int n = sidx[k];
        float v = xb[(size_t)c*N1 + n];
        if (c == 0) v -= c0; else if (c == 1) v -= c1; else if (c == 2) v -= c2;
        inb_[k][c] = v;
    }
    __syncthreads();
    {   // L1
        int o = t & 63, kg = t >> 6;
        float w[6];
#pragma unroll
        for (int c = 0; c < 6; ++c) w[c] = W1[o*6+c];
        float bias = B1[o];
#pragma unroll
        for (int kk = 0; kk < 8; ++kk) {
            int k = kg*8 + kk;
            float a = 0.f;
#pragma unroll
            for (int c = 0; c < 6; ++c) a = fmaf(inb_[k][c], w[c], a);
            h1_[k][o] = fmaxf(a + bias, 0.f);
        }
    }
    __syncthreads();
    {   // L2: 64 -> 64
        int o = t & 63, kg = t >> 6;
        float acc[8] = {};
        for (int ch = 0; ch < 8; ++ch) {
            const float4 wa = *(const float4*)&W2[o*64 + ch*8];
            const float4 wbv = *(const float4*)&W2[o*64 + ch*8 + 4];
#pragma unroll
            for (int kk = 0; kk < 8; ++kk) {
                int k = kg*8+kk;
                const float4 a0 = *(const float4*)&h1_[k][ch*8];
                const float4 a1 = *(const float4*)&h1_[k][ch*8+4];
                acc[kk] = fmaf(a0.x, wa.x, acc[kk]);
                acc[kk] = fmaf(a0.y, wa.y, acc[kk]);
                acc[kk] = fmaf(a0.z, wa.z, acc[kk]);
                acc[kk] = fmaf(a0.w, wa.w, acc[kk]);
                acc[kk] = fmaf(a1.x, wbv.x, acc[kk]);
                acc[kk] = fmaf(a1.y, wbv.y, acc[kk]);
                acc[kk] = fmaf(a1.z, wbv.z, acc[kk]);
                acc[kk] = fmaf(a1.w, wbv.w, acc[kk]);
            }
        }
        float bias = B2[o];
#pragma unroll
        for (int kk = 0; kk < 8; ++kk) h2_[kg*8+kk][o] = fmaxf(acc[kk] + bias, 0.f);
    }
    __syncthreads();
    {   // L3: 64 -> 128 + max over samples
        int o = t & 127, kg = t >> 7;
        float acc[16] = {};
        for (int ch = 0; ch < 8; ++ch) {
            const float4 wa = *(const float4*)&W3[o*64 + ch*8];
            const float4 wbv = *(const float4*)&W3[o*64 + ch*8 + 4];
#pragma unroll
            for (int kk = 0; kk < 16; ++kk) {
                int k = kg*16+kk;
                const float4 a0 = *(const float4*)&h2_[k][ch*8];
                const float4 a1 = *(const float4*)&h2_[k][ch*8+4];
                acc[kk] = fmaf(a0.x, wa.x, acc[kk]);
                acc[kk] = fmaf(a0.y, wa.y, acc[kk]);
                acc[kk] = fmaf(a0.z, wa.z, acc[kk]);
                acc[kk] = fmaf(a0.w, wa.w, acc[kk]);
                acc[kk] = fmaf(a1.x, wbv.x, acc[kk]);
                acc[kk] = fmaf(a1.y, wbv.y, acc[kk]);
                acc[kk] = fmaf(a1.z, wbv.z, acc[kk]);
                acc[kk] = fmaf(a1.w, wbv.w, acc[kk]);
            }
        }
        float bias = B3[o];
        float m = -1e30f;
#pragma unroll
        for (int kk = 0; kk < 16; ++kk) m = fmaxf(m, fmaxf(acc[kk] + bias, 0.f));
        red_[kg][o] = m;
    }
    __syncthreads();
    if (t < 128) {
        float m = fmaxf(red_[0][t], red_[1][t]);
        l1_points[((size_t)b*NP1+s)*128 + t] = m;   // (b, n, 128) layout
    }
}

// =====================  SA2 MLP (131->128->128->285) + maxpool over 64  =====================
// R6 version (known-good): feature-major LDS layout, float4 staging + float4
// LDS reads; L1/L2 compute 2 outputs/thread. Two sample-halves, < 64 KB LDS.
__global__ __launch_bounds__(256) void mlp2_kernel(
    const float* __restrict__ new_xyz1, const float* __restrict__ l1_points,
    const float* __restrict__ new_xyz2, const int* __restrict__ idx2,
    const float* __restrict__ W1, const float* __restrict__ B1,
    const float* __restrict__ W2, const float* __restrict__ B2,
    const float* __restrict__ W3, const float* __restrict__ B3,
    float* __restrict__ out1)
{
    const int s = blockIdx.x, b = blockIdx.y;
    const int t = threadIdx.x;
    __shared__ __align__(16) float inb_[32][132];   // 132 = pad to 16B rows
    __shared__ __align__(16) float h1_[32][128];
    __shared__ __align__(16) float h2_[32][128];
    __shared__ int sidx[NS2];

    const float* cp = new_xyz2 + ((size_t)b*NP2+s)*3;
    float c0=cp[0], c1=cp[1], c2=cp[2];
    if (t < NS2) sidx[t] = idx2[((size_t)b*NP2+s)*NS2 + t];

    const int o1 = t & 63, o2 = o1 + 64, g = t >> 6;   // L1/L2 mapping
    float vmax0 = -1e30f, vmax1 = -1e30f;              // L3: o=t and o=t+256

    for (int half = 0; half < 2; ++half) {
        __syncthreads();
        // stage: features via float4, then 3 relative coords
        for (int e = t; e < 32*32; e += 256) {
            int kk = e >> 5, c4 = e & 31;
            int n = sidx[half*32 + kk];
            *(float4*)&inb_[kk][c4*4] =
                *(const float4*)&l1_points[((size_t)b*N2 + n)*128 + c4*4];
        }
        for (int e = t; e < 32*3; e += 256) {
            int kk = e / 3, c = e % 3;
            int n = sidx[half*32 + kk];
            inb_[kk][128 + c] = new_xyz1[((size_t)b*N2 + n)*3 + c]
                              - (c==0 ? c0 : (c==1 ? c1 : c2));
        }
        __syncthreads();
        {   // L1: 131 -> 128, 2 outputs x 8 samples per thread
            float accA[8] = {}, accB[8] = {};
            for (int ch = 0; ch < 16; ++ch) {
                float wa[8], wbv[8];
#pragma unroll
                for (int j = 0; j < 8; ++j) {
                    wa[j]  = W1[o1*131 + 3 + ch*8 + j];   // feature cols are W1 cols 3..130
                    wbv[j] = W1[o2*131 + 3 + ch*8 + j];
                }
#pragma unroll
                for (int kk = 0; kk < 8; ++kk) {
                    int k = g*8 + kk;
                    const float4 a0 = *(const float4*)&inb_[k][ch*8];
                    const float4 a1 = *(const float4*)&inb_[k][ch*8+4];
                    accA[kk] = fmaf(a0.x, wa[0], accA[kk]);
                    accA[kk] = fmaf(a0.y, wa[1], accA[kk]);
                    accA[kk] = fmaf(a0.z, wa[2], accA[kk]);
                    accA[kk] = fmaf(a0.w, wa[3], accA[kk]);
                    accA[kk] = fmaf(a1.x, wa[4], accA[kk]);
                    accA[kk] = fmaf(a1.y, wa[5], accA[kk]);
                    accA[kk] = fmaf(a1.z, wa[6], accA[kk]);
                    accA[kk] = fmaf(a1.w, wa[7], accA[kk]);
                    accB[kk] = fmaf(a0.x, wbv[0], accB[kk]);
                    accB[kk] = fmaf(a0.y, wbv[1], accB[kk]);
                    accB[kk] = fmaf(a0.z, wbv[2], accB[kk]);
                    accB[kk] = fmaf(a0.w, wbv[3], accB[kk]);
                    accB[kk] = fmaf(a1.x, wbv[4], accB[kk]);
                    accB[kk] = fmaf(a1.y, wbv[5], accB[kk]);
                    accB[kk] = fmaf(a1.z, wbv[6], accB[kk]);
                    accB[kk] = fmaf(a1.w, wbv[7], accB[kk]);
                }
            }
            // coord tail (W1 cols 0..2)
            float ta0=W1[o1*131+0], ta1=W1[o1*131+1], ta2=W1[o1*131+2];
            float tb0=W1[o2*131+0], tb1=W1[o2*131+1], tb2=W1[o2*131+2];
            float biasA = B1[o1], biasB = B1[o2];
#pragma unroll
            for (int kk = 0; kk < 8; ++kk) {
                int k = g*8 + kk;
                float f0 = inb_[k][128], f1 = inb_[k][129], f2 = inb_[k][130];
                float vA = accA[kk];
                vA = fmaf(f0, ta0, vA); vA = fmaf(f1, ta1, vA); vA = fmaf(f2, ta2, vA);
                float vB = accB[kk];
                vB = fmaf(f0, tb0, vB); vB = fmaf(f1, tb1, vB); vB = fmaf(f2, tb2, vB);
                h1_[k][o1] = fmaxf(vA + biasA, 0.f);
                h1_[k][o2] = fmaxf(vB + biasB, 0.f);
            }
        }
        __syncthreads();
        {   // L2: 128 -> 128, 2 outputs x 8 samples per thread
            float accA[8] = {}, accB[8] = {};
            for (int ch = 0; ch < 16; ++ch) {
                const float4 wa0 = *(const float4*)&W2[o1*128 + ch*8];
                const float4 wa1 = *(const float4*)&W2[o1*128 + ch*8 + 4];
                const float4 wb0 = *(const float4*)&W2[o2*128 + ch*8];
                const float4 wb1 = *(const float4*)&W2[o2*128 + ch*8 + 4];
#pragma unroll
                for (int kk = 0; kk < 8; ++kk) {
                    int k = g*8 + kk;
                    const float4 a0 = *(const float4*)&h1_[k][ch*8];
                    const float4 a1 = *(const float4*)&h1_[k][ch*8+4];
                    accA[kk] = fmaf(a0.x, wa0.x, accA[kk]);
                    accA[kk] = fmaf(a0.y, wa0.y, accA[kk]);
                    accA[kk] = fmaf(a0.z, wa0.z, accA[kk]);
                    accA[kk] = fmaf(a0.w, wa0.w, accA[kk]);
                    accA[kk] = fmaf(a1.x, wa1.x, accA[kk]);
                    accA[kk] = fmaf(a1.y, wa1.y, accA[kk]);
                    accA[kk] = fmaf(a1.z, wa1.z, accA[kk]);
                    accA[kk] = fmaf(a1.w, wa1.w, accA[kk]);
                    accB[kk] = fmaf(a0.x, wb0.x, accB[kk]);
                    accB[kk] = fmaf(a0.y, wb0.y, accB[kk]);
                    accB[kk] = fmaf(a0.z, wb0.z, accB[kk]);
                    accB[kk] = fmaf(a0.w, wb0.w, accB[kk]);
                    accB[kk] = fmaf(a1.x, wb1.x, accB[kk]);
                    accB[kk] = fmaf(a1.y, wb1.y, accB[kk]);
                    accB[kk] = fmaf(a1.z, wb1.z, accB[kk]);
                    accB[kk] = fmaf(a1.w, wb1.w, accB[kk]);
                }
            }
            float biasA = B2[o1], biasB = B2[o2];
#pragma unroll
            for (int kk = 0; kk < 8; ++kk) {
                int k = g*8 + kk;
                h2_[k][o1] = fmaxf(accA[kk] + biasA, 0.f);
                h2_[k][o2] = fmaxf(accB[kk] + biasB, 0.f);
            }
        }
        __syncthreads();
        {   // L3: 128 -> 285, fold max over this half's 32 samples
            {
                float acc[32] = {};
                for (int ch = 0; ch < 16; ++ch) {
                    const float4 w0 = *(const float4*)&W3[t*128 + ch*8];
                    const float4 w1 = *(const float4*)&W3[t*128 + ch*8 + 4];
#pragma unroll
                    for (int kk = 0; kk < 32; ++kk) {
                        const float4 a0 = *(const float4*)&h2_[kk][ch*8];
                        const float4 a1 = *(const float4*)&h2_[kk][ch*8+4];
                        acc[kk] = fmaf(a0.x, w0.x, acc[kk]);
                        acc[kk] = fmaf(a0.y, w0.y, acc[kk]);
                        acc[kk] = fmaf(a0.z, w0.z, acc[kk]);
                        acc[kk] = fmaf(a0.w, w0.w, acc[kk]);
                        acc[kk] = fmaf(a1.x, w1.x, acc[kk]);
                        acc[kk] = fmaf(a1.y, w1.y, acc[kk]);
                        acc[kk] = fmaf(a1.z, w1.z, acc[kk]);
                        acc[kk] = fmaf(a1.w, w1.w, acc[kk]);
                    }
                }
                float bias = B3[t];
                float mm = vmax0;
#pragma unroll
                for (int kk = 0; kk < 32; ++kk) mm = fmaxf(mm, fmaxf(acc[kk] + bias, 0.f));
                vmax0 = mm;
            }
            if (t < 29) {
                int o = t + 256;
                float acc[32] = {};
                for (int ch = 0; ch < 16; ++ch) {
                    const float4 w0 = *(const float4*)&W3[o*128 + ch*8];
                    const float4 w1 = *(const float4*)&W3[o*128 + ch*8 + 4];
#pragma unroll
                    for (int kk = 0; kk < 32; ++kk) {
                        const float4 a0 = *(const float4*)&h2_[kk][ch*8];
                        const float4 a1 = *(const float4*)&h2_[kk][ch*8+4];
                        acc[kk] = fmaf(a0.x, w0.x, acc[kk]);
                        acc[kk] = fmaf(a0.y, w0.y, acc[kk]);
                        acc[kk] = fmaf(a0.z, w0.z, acc[kk]);
                        acc[kk] = fmaf(a0.w, w0.w, acc[kk]);
                        acc[kk] = fmaf(a1.x, w1.x, acc[kk]);
                        acc[kk] = fmaf(a1.y, w1.y, acc[kk]);
                        acc[kk] = fmaf(a1.z, w1.z, acc[kk]);
                        acc[kk] = fmaf(a1.w, w1.w, acc[kk]);
                    }
                }
                float bias = B3[o];
                float mm = vmax1;
#pragma unroll
                for (int kk = 0; kk < 32; ++kk) mm = fmaxf(mm, fmaxf(acc[kk] + bias, 0.f));
                vmax1 = mm;
            }
        }
    }
    out1[((size_t)b*NP2+s)*285 + t] = vmax0;
    if (t < 29) out1[((size_t)b*NP2+s)*285 + t + 256] = vmax1;
}

extern "C" void kernel_launch(void* const* d_in, const int* in_sizes, int n_in,
                              void* d_out, int out_size, void* d_ws, size_t ws_size,
                              hipStream_t stream)
{
    (void)in_sizes; (void)n_in; (void)out_size; (void)ws_size;
    const float* xyz  = (const float*)d_in[0];
    const float* s1w1 = (const float*)d_in[1];  const float* s1b1 = (const float*)d_in[2];
    const float* s1w2 = (const float*)d_in[3];  const float* s1b2 = (const float*)d_in[4];
    const float* s1w3 = (const float*)d_in[5];  const float* s1b3 = (const float*)d_in[6];
    const float* s2w1 = (const float*)d_in[7];  const float* s2b1 = (const float*)d_in[8];
    const float* s2w2 = (const float*)d_in[9];  const float* s2b2 = (const float*)d_in[10];
    const float* s2w3 = (const float*)d_in[11]; const float* s2b3 = (const float*)d_in[12];

    float* ws        = (float*)d_ws;
    float* new_xyz1  = ws;                  // 8*512*3   = 12288 f
    float* new_xyz2  = ws + 12288;          // 8*256*3   = 6144 f
    float* l1_points = ws + 18432;          // 8*512*128 = 524288 f
    int*   idx1      = (int*)(ws + 542720); // 8*512*32  = 131072 i
    int*   idx2      = idx1 + 131072;       // 8*256*64  = 131072 i
    // fps1 exchange slots: 8 batches x 2 parities x 64 wave-slots u64 (8 KB)
    unsigned long long* bests = (unsigned long long*)(ws + 804864);

    float* out0 = (float*)d_out;            // (8,3,256)
    float* out1 = out0 + 8*3*256;           // (8,256,285)

    const float r2a = (float)(0.025*0.025);
    const float r2b = (float)(0.05*0.05);

    fps1_kernel <<<dim3(FPS1_M, 8), dim3(FPS1_TB), 0, stream>>>(xyz, new_xyz1, bests);
    ball1_kernel<<<dim3(NP1, 8),    dim3(64),      0, stream>>>(xyz, new_xyz1, idx1, r2a);
    mlp1_kernel <<<dim3(NP1, 8),    dim3(256),     0, stream>>>(xyz, new_xyz1, idx1,
                    s1w1,s1b1,s1w2,s1b2,s1w3,s1b3, l1_points);
    fps2_kernel <<<dim3(8),         dim3(64),      0, stream>>>(new_xyz1, new_xyz2, out0);
    ball2_kernel<<<dim3(NP2, 8),    dim3(64),      0, stream>>>(new_xyz1, new_xyz2, idx2, r2b);
    mlp2_kernel <<<dim3(NP2, 8),    dim3(256),     0, stream>>>(new_xyz1, l1_points, new_xyz2, idx2,
                    s2w1,s2b1,s2w2,s2b2,s2w3,s2b3, out1);
}